// Round 1
// baseline (342.693 us; speedup 1.0000x reference)
//
#include <hip/hip_runtime.h>

#define T_ 16
#define N_ 128
#define F_ 128

__device__ __forceinline__ float fast_tanh(float x) {
    // tanh(x) = 1 - 2/(exp(2x)+1); v_exp_f32 + native rcp-div. Handles +-inf correctly.
    float e = __expf(2.0f * x);
    return 1.0f - __fdividef(2.0f, e + 1.0f);
}

__device__ __forceinline__ float lrelu(float v) {
    return v >= 0.0f ? v : 0.01f * v;
}

// ---------------- sim_cal: out[t,0,n,m]=clip(sim), out[t,1,n,m]=clip(1-sim) ----------------
// grid (T, 8), block 128. Each block: full X[t] in LDS, computes 16 n-rows x 128 m-cols.
__global__ __launch_bounds__(128) void sim_cal_k(const float* __restrict__ x,
                                                 float* __restrict__ out) {
    __shared__ float Xs[128][132];   // pad 132: 16B-aligned rows
    __shared__ float nrm[128];
    int t = blockIdx.x, ch = blockIdx.y;
    int m = threadIdx.x;
    const float* xt = x + (size_t)t * (N_ * F_);

    // cooperative load, coalesced float4
    int fg = (m & 31) * 4, ko = m >> 5;
    for (int kb = 0; kb < 128; kb += 4) {
        int k = kb + ko;
        float4 v = *(const float4*)(xt + k * 128 + fg);
        *(float4*)&Xs[k][fg] = v;
    }
    __syncthreads();

    // norm of row m
    float s = 0.0f;
    #pragma unroll 8
    for (int f = 0; f < 128; f += 4) {
        float4 v = *(float4*)&Xs[m][f];
        s += v.x * v.x + v.y * v.y + v.z * v.z + v.w * v.w;
    }
    nrm[m] = sqrtf(s);
    __syncthreads();

    float acc[16];
    #pragma unroll
    for (int r = 0; r < 16; ++r) acc[r] = 0.0f;

    for (int fc = 0; fc < 128; fc += 32) {
        float xm[32];
        #pragma unroll
        for (int f = 0; f < 32; f += 4) {
            float4 v = *(float4*)&Xs[m][fc + f];
            xm[f] = v.x; xm[f + 1] = v.y; xm[f + 2] = v.z; xm[f + 3] = v.w;
        }
        #pragma unroll
        for (int r = 0; r < 16; ++r) {
            int n = ch * 16 + r;
            #pragma unroll
            for (int f = 0; f < 32; f += 4) {
                float4 v = *(float4*)&Xs[n][fc + f];
                acc[r] = fmaf(xm[f], v.x,
                         fmaf(xm[f + 1], v.y,
                         fmaf(xm[f + 2], v.z,
                         fmaf(xm[f + 3], v.w, acc[r]))));
            }
        }
    }

    float nm = nrm[m];
    size_t ob = (size_t)t * 2 * 16384;
    #pragma unroll
    for (int r = 0; r < 16; ++r) {
        int n = ch * 16 + r;
        float denom = nrm[n] * nm + 1e-6f;
        float sim = __fdividef(acc[r], denom);
        float s0 = fminf(fmaxf(sim, 0.0f), 1.0f);
        float s1 = fminf(fmaxf(1.0f - sim, 0.0f), 1.0f);
        out[ob + (size_t)n * 128 + m] = s0;
        out[ob + 16384 + (size_t)n * 128 + m] = s1;
    }
}

// ---------------- edge update + aggregate, layer 0 ----------------
// grid 2048 (= t*128+i), block 128. thread = (jl 0..3, fg 0..31); float4 over features.
__global__ __launch_bounds__(128) void edge_aggr_l0(const float* __restrict__ x0,
                                                    const float* __restrict__ E,
                                                    const float* __restrict__ ew,
                                                    const float* __restrict__ eb,
                                                    float* __restrict__ aggr) {
    int ti = blockIdx.x;
    int t = ti >> 7, i = ti & 127;
    int tid = threadIdx.x;
    int jl = tid >> 5, fg = tid & 31;
    float w0 = ew[0], w1 = ew[1], w2 = ew[2], b = eb[0];
    const float4* xt = (const float4*)(x0 + (size_t)t * 16384);
    const float4* Ei = (const float4*)(E + (size_t)ti * 16384);
    float4 xi = xt[i * 32 + fg];
    float ax = 0.0f, ay = 0.0f, az = 0.0f, aw = 0.0f;
    #pragma unroll 4
    for (int jb = 0; jb < 128; jb += 4) {
        int j = jb + jl;
        float4 xj = xt[j * 32 + fg];
        float4 ev = Ei[j * 32 + fg];
        if (j != i) {
            ax += fast_tanh(fmaf(w0, xi.x, fmaf(w1, xi.x - xj.x, fmaf(w2, ev.x, b))));
            ay += fast_tanh(fmaf(w0, xi.y, fmaf(w1, xi.y - xj.y, fmaf(w2, ev.y, b))));
            az += fast_tanh(fmaf(w0, xi.z, fmaf(w1, xi.z - xj.z, fmaf(w2, ev.z, b))));
            aw += fast_tanh(fmaf(w0, xi.w, fmaf(w1, xi.w - xj.w, fmaf(w2, ev.w, b))));
        }
    }
    __shared__ float4 red[128];
    red[tid] = make_float4(ax, ay, az, aw);
    __syncthreads();
    if (tid < 32) {
        float4 a = red[tid], b4 = red[tid + 32], c = red[tid + 64], d = red[tid + 96];
        float4 r;
        r.x = a.x + b4.x + c.x + d.x;
        r.y = a.y + b4.y + c.y + d.y;
        r.z = a.z + b4.z + c.z + d.z;
        r.w = a.w + b4.w + c.w + d.w;
        ((float4*)aggr)[(size_t)ti * 32 + tid] = r;
    }
}

// ---------------- edge update + aggregate, layer 1 (recompute e0 from original E) ----------------
__global__ __launch_bounds__(128) void edge_aggr_l1(const float* __restrict__ x0,
                                                    const float* __restrict__ x1,
                                                    const float* __restrict__ E,
                                                    const float* __restrict__ ew,
                                                    const float* __restrict__ eb,
                                                    float* __restrict__ aggr) {
    int ti = blockIdx.x;
    int t = ti >> 7, i = ti & 127;
    int tid = threadIdx.x;
    int jl = tid >> 5, fg = tid & 31;
    float w00 = ew[0], w01 = ew[1], w02 = ew[2], b0 = eb[0];
    float w10 = ew[3], w11 = ew[4], w12 = ew[5], b1 = eb[1];
    const float4* xt0 = (const float4*)(x0 + (size_t)t * 16384);
    const float4* xt1 = (const float4*)(x1 + (size_t)t * 16384);
    const float4* Ei = (const float4*)(E + (size_t)ti * 16384);
    float4 xi0 = xt0[i * 32 + fg];
    float4 xi1 = xt1[i * 32 + fg];
    float ax = 0.0f, ay = 0.0f, az = 0.0f, aw = 0.0f;
    #pragma unroll 2
    for (int jb = 0; jb < 128; jb += 4) {
        int j = jb + jl;
        float4 xj0 = xt0[j * 32 + fg];
        float4 xj1 = xt1[j * 32 + fg];
        float4 ev = Ei[j * 32 + fg];
        if (j != i) {
            float e0x = fast_tanh(fmaf(w00, xi0.x, fmaf(w01, xi0.x - xj0.x, fmaf(w02, ev.x, b0))));
            float e0y = fast_tanh(fmaf(w00, xi0.y, fmaf(w01, xi0.y - xj0.y, fmaf(w02, ev.y, b0))));
            float e0z = fast_tanh(fmaf(w00, xi0.z, fmaf(w01, xi0.z - xj0.z, fmaf(w02, ev.z, b0))));
            float e0w = fast_tanh(fmaf(w00, xi0.w, fmaf(w01, xi0.w - xj0.w, fmaf(w02, ev.w, b0))));
            ax += fast_tanh(fmaf(w10, xi1.x, fmaf(w11, xi1.x - xj1.x, fmaf(w12, e0x, b1))));
            ay += fast_tanh(fmaf(w10, xi1.y, fmaf(w11, xi1.y - xj1.y, fmaf(w12, e0y, b1))));
            az += fast_tanh(fmaf(w10, xi1.z, fmaf(w11, xi1.z - xj1.z, fmaf(w12, e0z, b1))));
            aw += fast_tanh(fmaf(w10, xi1.w, fmaf(w11, xi1.w - xj1.w, fmaf(w12, e0w, b1))));
        }
    }
    __shared__ float4 red[128];
    red[tid] = make_float4(ax, ay, az, aw);
    __syncthreads();
    if (tid < 32) {
        float4 a = red[tid], b4 = red[tid + 32], c = red[tid + 64], d = red[tid + 96];
        float4 r;
        r.x = a.x + b4.x + c.x + d.x;
        r.y = a.y + b4.y + c.y + d.y;
        r.z = a.z + b4.z + c.z + d.z;
        r.w = a.w + b4.w + c.w + d.w;
        ((float4*)aggr)[(size_t)ti * 32 + tid] = r;
    }
}

// ---------------- transpose node_w for coalesced GEMM loads ----------------
__global__ void transpose_w(const float* __restrict__ W, float* __restrict__ WT) {
    int l = blockIdx.y;
    int idx = blockIdx.x * 256 + threadIdx.x;   // 0..16383
    int g = idx >> 7, f = idx & 127;
    WT[l * 16384 + f * 128 + g] = W[l * 16384 + idx];
}

__global__ void zero_bn(float* __restrict__ bn) {
    bn[threadIdx.x] = 0.0f;
}

// ---------------- node update: h=lrelu(c0*x+c1*aggr); y = h @ W^T; BN partial sums ----------------
// grid (T, 16), block 128 (thread = g). ag_y buffer: read as aggr, overwritten with y (disjoint per block).
#define ROWS 8
__global__ __launch_bounds__(128) void node_update(const float* __restrict__ x,
                                                   float* ag_y,
                                                   const float* __restrict__ cw,
                                                   const float* __restrict__ WT,
                                                   float* __restrict__ bn) {
    __shared__ float hs[ROWS][128];
    int t = blockIdx.x, ch = blockIdx.y, g = threadIdx.x;
    float c0 = cw[0], c1 = cw[1];
    size_t base = ((size_t)t * 128 + ch * ROWS) * 128;
    #pragma unroll
    for (int r = 0; r < ROWS; ++r) {
        float xv = x[base + r * 128 + g];
        float av = ag_y[base + r * 128 + g];
        hs[r][g] = lrelu(fmaf(c0, xv, c1 * av));
    }
    __syncthreads();
    float acc[ROWS];
    #pragma unroll
    for (int r = 0; r < ROWS; ++r) acc[r] = 0.0f;
    #pragma unroll 4
    for (int f2 = 0; f2 < 128; ++f2) {
        float wv = WT[f2 * 128 + g];
        #pragma unroll
        for (int r = 0; r < ROWS; ++r) acc[r] = fmaf(hs[r][f2], wv, acc[r]);
    }
    float s = 0.0f, ss = 0.0f;
    #pragma unroll
    for (int r = 0; r < ROWS; ++r) {
        ag_y[base + r * 128 + g] = acc[r];
        s += acc[r];
        ss += acc[r] * acc[r];
    }
    atomicAdd(&bn[g], s);
    atomicAdd(&bn[128 + g], ss);
}

// ---------------- BN apply + lrelu -> next node feats ----------------
__global__ void bn_apply(const float* __restrict__ y, const float* __restrict__ bn,
                         const float* __restrict__ gamma, const float* __restrict__ beta,
                         float* __restrict__ xout) {
    int idx = blockIdx.x * 256 + threadIdx.x;   // T*N*F = 262144
    int g = idx & 127;
    float mu = bn[g] * (1.0f / 2048.0f);
    float var = bn[128 + g] * (1.0f / 2048.0f) - mu * mu;
    float inv = rsqrtf(var + 1e-5f);
    float v = (y[idx] - mu) * inv * gamma[g] + beta[g];
    xout[idx] = lrelu(v);
}

extern "C" void kernel_launch(void* const* d_in, const int* in_sizes, int n_in,
                              void* d_out, int out_size, void* d_ws, size_t ws_size,
                              hipStream_t stream) {
    const float* x0    = (const float*)d_in[0];
    const float* E     = (const float*)d_in[1];
    const float* ew    = (const float*)d_in[2];
    const float* eb    = (const float*)d_in[3];
    const float* cw    = (const float*)d_in[4];
    const float* nw    = (const float*)d_in[5];
    const float* gamma = (const float*)d_in[6];
    const float* beta  = (const float*)d_in[7];
    float* out = (float*)d_out;

    float* ws  = (float*)d_ws;
    float* x1  = ws;                 // 262144
    float* x2  = ws + 262144;        // 262144
    float* yag = ws + 524288;        // 262144 (aggr & y shared)
    float* bn  = ws + 786432;        // 256
    float* WT  = ws + 786688;        // 32768 (both layers)

    transpose_w<<<dim3(64, 2), 256, 0, stream>>>(nw, WT);

    // out[0] = sim_cal(x0)
    sim_cal_k<<<dim3(16, 8), 128, 0, stream>>>(x0, out);

    // layer 0
    edge_aggr_l0<<<2048, 128, 0, stream>>>(x0, E, ew, eb, yag);
    zero_bn<<<1, 256, 0, stream>>>(bn);
    node_update<<<dim3(16, 16), 128, 0, stream>>>(x0, yag, cw, WT, bn);
    bn_apply<<<1024, 256, 0, stream>>>(yag, bn, gamma, beta, x1);
    sim_cal_k<<<dim3(16, 8), 128, 0, stream>>>(x1, out + 524288);

    // layer 1 (recompute e0 from original E on the fly)
    edge_aggr_l1<<<2048, 128, 0, stream>>>(x0, x1, E, ew, eb, yag);
    zero_bn<<<1, 256, 0, stream>>>(bn);
    node_update<<<dim3(16, 16), 128, 0, stream>>>(x1, yag, cw + 2, WT + 16384, bn);
    bn_apply<<<1024, 256, 0, stream>>>(yag, bn, gamma + 128, beta + 128, x2);
    sim_cal_k<<<dim3(16, 8), 128, 0, stream>>>(x2, out + 1048576);
}